// Round 5
// baseline (222.119 us; speedup 1.0000x reference)
//
#include <hip/hip_runtime.h>

// Yolov6 assigner pre-computation, split into three plane-specialized
// kernels (R7 discriminator):
//   distances[g][j] = ||center(gt_flat[g]) - center(anchor[j])||        (2048 x 8400)
//   overlaps[b][m][j] = IoU(gt[b][m], pred[b][j])   eps=1e-9 (added)    (16 x 128 x 8400)
//   gious[g][j]      = GIoU(gt_flat[g], anchor[j])  eps=1e-6 (clamped)  (2048 x 8400)
//
// Rationale: R5/R6 falsified ALU, grid, occupancy, store-width and
// store-policy theories (all flat). The only untested structural
// difference vs the 6.5 TB/s harness fill is that the fused kernel
// interleaves THREE write streams 68.8 MB apart per wave (DRAM open-page
// working set 3x). Each split kernel is a pure single-stream writer,
// fill-identical pattern: per wave 1 KB contiguous, per block 4 KB
// contiguous per row. Inputs (2.3 MB) are L3-resident, so the 3x
// geometry recompute is free (~11 us issue vs 33 us write floor).

#define EPS_IOU 1e-9f
#define EPS_OVL 1e-6f
#define ROWS 4

__device__ __forceinline__ float frcp(float x)   { return __builtin_amdgcn_rcpf(x); }
__device__ __forceinline__ float fsqrtf_(float x){ return __builtin_amdgcn_sqrtf(x); }

// ---------------- distances: gt x anchor centers ----------------
__global__ __launch_bounds__(256) void k_dist(
    const float4* __restrict__ gt, const float4* __restrict__ anc,
    float* __restrict__ out, int N, int qcols, int total)
{
    const int t = blockIdx.x * blockDim.x + threadIdx.x;
    if (t >= total) return;
    const int rb = t / qcols;
    const int c  = t - rb * qcols;
    const int j  = c * 4;
    if (j >= N) return;
    const int g0 = rb * ROWS;

    float acx[4], acy[4];
#pragma unroll
    for (int k = 0; k < 4; ++k) {
        float4 a = anc[j + k];
        acx[k] = (a.x + a.z) * 0.5f;
        acy[k] = (a.y + a.w) * 0.5f;
    }
#pragma unroll
    for (int r = 0; r < ROWS; ++r) {
        const float4 gb = gt[g0 + r];
        const float gcx = (gb.x + gb.z) * 0.5f;
        const float gcy = (gb.y + gb.w) * 0.5f;
        float dv[4];
#pragma unroll
        for (int k = 0; k < 4; ++k) {
            float dx = gcx - acx[k], dy = gcy - acy[k];
            dv[k] = fsqrtf_(dx * dx + dy * dy);
        }
        *(float4*)(out + (long long)(g0 + r) * N + j) =
            make_float4(dv[0], dv[1], dv[2], dv[3]);
    }
}

// ---------------- gious: gt x anchor ----------------
__global__ __launch_bounds__(256) void k_giou(
    const float4* __restrict__ gt, const float4* __restrict__ anc,
    float* __restrict__ out, int N, int qcols, int total)
{
    const int t = blockIdx.x * blockDim.x + threadIdx.x;
    if (t >= total) return;
    const int rb = t / qcols;
    const int c  = t - rb * qcols;
    const int j  = c * 4;
    if (j >= N) return;
    const int g0 = rb * ROWS;

    float4 ab[4]; float aarea[4];
#pragma unroll
    for (int k = 0; k < 4; ++k) {
        ab[k] = anc[j + k];
        aarea[k] = (ab[k].z - ab[k].x) * (ab[k].w - ab[k].y);
    }
#pragma unroll
    for (int r = 0; r < ROWS; ++r) {
        const float4 gb = gt[g0 + r];
        const float garea = (gb.z - gb.x) * (gb.w - gb.y);
        float gv[4];
#pragma unroll
        for (int k = 0; k < 4; ++k) {
            float ltx = fmaxf(gb.x, ab[k].x), lty = fmaxf(gb.y, ab[k].y);
            float rbx = fminf(gb.z, ab[k].z), rby = fminf(gb.w, ab[k].w);
            float w = fmaxf(rbx - ltx, 0.0f), h = fmaxf(rby - lty, 0.0f);
            float overlap = w * h;
            float uni = fmaxf(garea + aarea[k] - overlap, EPS_OVL);
            float elx = fminf(gb.x, ab[k].x), ely = fminf(gb.y, ab[k].y);
            float erx = fmaxf(gb.z, ab[k].z), ery = fmaxf(gb.w, ab[k].w);
            float ew = fmaxf(erx - elx, 0.0f), eh = fmaxf(ery - ely, 0.0f);
            float earea = fmaxf(ew * eh, EPS_OVL);
            // overlap/uni - (earea-uni)/earea, single rcp
            float num = overlap * earea - (earea - uni) * uni;
            gv[k] = num * frcp(uni * earea);
        }
        *(float4*)(out + (long long)(g0 + r) * N + j) =
            make_float4(gv[0], gv[1], gv[2], gv[3]);
    }
}

// ---------------- overlaps: gt x pred (per batch) ----------------
__global__ __launch_bounds__(256) void k_ovl(
    const float4* __restrict__ gt, const float4* __restrict__ pred,
    float* __restrict__ out, int N, int M, int qcols, int total)
{
    const int t = blockIdx.x * blockDim.x + threadIdx.x;
    if (t >= total) return;
    const int rb = t / qcols;
    const int c  = t - rb * qcols;
    const int j  = c * 4;
    if (j >= N) return;
    const int g0 = rb * ROWS;
    const int b  = g0 / M;                 // ROWS | M so all rows share b

    float4 pb[4]; float parea[4];
    const float4* predp = pred + (long long)b * N + j;
#pragma unroll
    for (int k = 0; k < 4; ++k) {
        pb[k] = predp[k];
        parea[k] = (pb[k].z - pb[k].x) * (pb[k].w - pb[k].y);
    }
#pragma unroll
    for (int r = 0; r < ROWS; ++r) {
        const float4 gb = gt[g0 + r];
        const float garea = (gb.z - gb.x) * (gb.w - gb.y);
        float ov[4];
#pragma unroll
        for (int k = 0; k < 4; ++k) {
            float ltx = fmaxf(gb.x, pb[k].x), lty = fmaxf(gb.y, pb[k].y);
            float rbx = fminf(gb.z, pb[k].z), rby = fminf(gb.w, pb[k].w);
            float w = fmaxf(rbx - ltx, 0.0f), h = fmaxf(rby - lty, 0.0f);
            float overlap = w * h;
            float uni = garea + parea[k] - overlap + EPS_IOU;
            ov[k] = overlap * frcp(uni);
        }
        *(float4*)(out + (long long)(g0 + r) * N + j) =
            make_float4(ov[0], ov[1], ov[2], ov[3]);
    }
}

extern "C" void kernel_launch(void* const* d_in, const int* in_sizes, int n_in,
                              void* d_out, int out_size, void* d_ws, size_t ws_size,
                              hipStream_t stream) {
    const float4* gt   = (const float4*)d_in[0];
    const float4* pred = (const float4*)d_in[1];
    const float4* anc  = (const float4*)d_in[2];

    const int N  = in_sizes[2] / 4;           // 8400 anchors
    const int bs = in_sizes[1] / in_sizes[2]; // 16
    const int GM = in_sizes[0] / 4;           // bs*M = 2048
    const int M  = GM / bs;                   // 128

    float* out = (float*)d_out;
    const long long plane = (long long)GM * N;
    float* out_dist = out;
    float* out_ovl  = out + plane;
    float* out_giou = out + 2 * plane;

    const int qcols = (N + 3) / 4;            // 2100 threads per row-block
    const int total = (GM / ROWS) * qcols;    // 512 * 2100 = 1,075,200
    dim3 block(256);
    dim3 grid((total + 255) / 256);           // 4200 blocks per kernel

    k_dist<<<grid, block, 0, stream>>>(gt, anc,  out_dist, N, qcols, total);
    k_ovl <<<grid, block, 0, stream>>>(gt, pred, out_ovl,  N, M, qcols, total);
    k_giou<<<grid, block, 0, stream>>>(gt, anc,  out_giou, N, qcols, total);
}

// Round 6
// 209.693 us; speedup vs baseline: 1.0593x; 1.0593x over previous
//
#include <hip/hip_runtime.h>

// Yolov6 assigner pre-computation, fused (single launch):
//   distances[g][j] = ||center(gt_flat[g]) - center(anchor[j])||        (2048 x 8400)
//   overlaps[b][m][j] = IoU(gt[b][m], pred[b][j])   eps=1e-9 (added)    (16 x 128 x 8400)
//   gious[g][j]      = GIoU(gt_flat[g], anchor[j])  eps=1e-6 (clamped)  (2048 x 8400)
//
// R8 = revert of the R7 3-kernel split (which regressed by ~2 launch+ramp
// costs). Standing model after R5-R7 falsified ALL issue-side levers
// (ALU count, grid exactness, occupancy, store width, nt policy, stream
// split): kernel is at its 206.4 MB / 6.6 TB/s = ~31 us write roofline;
// the ~205 us envelope is dominated by the harness reset (824 MB poison
// fill ~124 us + dozens of tiny memset dispatches ~45 us). Therefore:
// ONE kernel launch, coalesced float4 stores, exact-fit grid, single-rcp
// GIoU, fast rcp/sqrt (absmax tolerance 4.0 >> 1-ulp approx error).

#define EPS_IOU 1e-9f
#define EPS_OVL 1e-6f
#define ROWS 4

__device__ __forceinline__ float frcp(float x)   { return __builtin_amdgcn_rcpf(x); }
__device__ __forceinline__ float fsqrtf_(float x){ return __builtin_amdgcn_sqrtf(x); }

__global__ __launch_bounds__(256) void yolov6_fused(
    const float4* __restrict__ gt,    // bs*M boxes
    const float4* __restrict__ pred,  // bs*N boxes
    const float4* __restrict__ anc,   // N boxes
    float* __restrict__ out_dist,
    float* __restrict__ out_ovl,
    float* __restrict__ out_giou,
    int N, int M, int qcols, int total)   // qcols = ceil(N/4) threads per row-block
{
    const int t = blockIdx.x * blockDim.x + threadIdx.x;
    if (t >= total) return;               // exact fit for the bench shape (no-op)

    const int rb = t / qcols;             // row-block index
    const int c  = t - rb * qcols;
    const int j  = c * 4;                 // first anchor column (in boxes)
    if (j >= N) return;                   // defensive (never taken when 4|N)
    const int g0 = rb * ROWS;
    const int b  = g0 / M;                // ROWS | M so all ROWS rows share b

    // Load this thread's 4 anchor and 4 pred boxes ONCE; precompute
    // column-only quantities.
    float4 ab[4], pb[4];
    float acx[4], acy[4], aarea[4], parea[4];
    const float4* ancp  = anc + j;
    const float4* predp = pred + (long long)b * N + j;
#pragma unroll
    for (int k = 0; k < 4; ++k) {
        ab[k] = ancp[k];
        pb[k] = predp[k];
        acx[k]   = (ab[k].x + ab[k].z) * 0.5f;
        acy[k]   = (ab[k].y + ab[k].w) * 0.5f;
        aarea[k] = (ab[k].z - ab[k].x) * (ab[k].w - ab[k].y);
        parea[k] = (pb[k].z - pb[k].x) * (pb[k].w - pb[k].y);
    }

#pragma unroll
    for (int r = 0; r < ROWS; ++r) {
        const int g = g0 + r;
        const float4 gb = gt[g];          // wave-uniform except at rb seams
        const float gcx   = (gb.x + gb.z) * 0.5f;
        const float gcy   = (gb.y + gb.w) * 0.5f;
        const float garea = (gb.z - gb.x) * (gb.w - gb.y);

        float dv[4], ov[4], gv[4];
#pragma unroll
        for (int k = 0; k < 4; ++k) {
            // distance
            float dx = gcx - acx[k], dy = gcy - acy[k];
            dv[k] = fsqrtf_(dx * dx + dy * dy);
            // GIoU vs anchor — single rcp:
            //   overlap/uni - (earea-uni)/earea
            // = (overlap*earea - (earea-uni)*uni) * rcp(uni*earea)
            {
                float ltx = fmaxf(gb.x, ab[k].x), lty = fmaxf(gb.y, ab[k].y);
                float rbx = fminf(gb.z, ab[k].z), rby = fminf(gb.w, ab[k].w);
                float w = fmaxf(rbx - ltx, 0.0f), h = fmaxf(rby - lty, 0.0f);
                float overlap = w * h;
                float uni = fmaxf(garea + aarea[k] - overlap, EPS_OVL);
                float elx = fminf(gb.x, ab[k].x), ely = fminf(gb.y, ab[k].y);
                float erx = fmaxf(gb.z, ab[k].z), ery = fmaxf(gb.w, ab[k].w);
                float ew = fmaxf(erx - elx, 0.0f), eh = fmaxf(ery - ely, 0.0f);
                float earea = fmaxf(ew * eh, EPS_OVL);
                float num = overlap * earea - (earea - uni) * uni;
                gv[k] = num * frcp(uni * earea);
            }
            // IoU vs pred
            {
                float ltx = fmaxf(gb.x, pb[k].x), lty = fmaxf(gb.y, pb[k].y);
                float rbx = fminf(gb.z, pb[k].z), rby = fminf(gb.w, pb[k].w);
                float w = fmaxf(rbx - ltx, 0.0f), h = fmaxf(rby - lty, 0.0f);
                float overlap = w * h;
                float uni = garea + parea[k] - overlap + EPS_IOU;
                ov[k] = overlap * frcp(uni);
            }
        }
        const long long row = (long long)g * N + j;
        *(float4*)(out_dist + row) = make_float4(dv[0], dv[1], dv[2], dv[3]);
        *(float4*)(out_ovl  + row) = make_float4(ov[0], ov[1], ov[2], ov[3]);
        *(float4*)(out_giou + row) = make_float4(gv[0], gv[1], gv[2], gv[3]);
    }
}

extern "C" void kernel_launch(void* const* d_in, const int* in_sizes, int n_in,
                              void* d_out, int out_size, void* d_ws, size_t ws_size,
                              hipStream_t stream) {
    const float4* gt   = (const float4*)d_in[0];
    const float4* pred = (const float4*)d_in[1];
    const float4* anc  = (const float4*)d_in[2];

    const int N  = in_sizes[2] / 4;           // 8400 anchors
    const int bs = in_sizes[1] / in_sizes[2]; // 16
    const int GM = in_sizes[0] / 4;           // bs*M = 2048
    const int M  = GM / bs;                   // 128

    float* out = (float*)d_out;
    const long long plane = (long long)GM * N;
    float* out_dist = out;
    float* out_ovl  = out + plane;
    float* out_giou = out + 2 * plane;

    const int qcols = (N + 3) / 4;            // 2100 threads per row-block
    const int total = (GM / ROWS) * qcols;    // 512 * 2100 = 1,075,200 (= 4200*256)
    dim3 block(256);
    dim3 grid((total + 255) / 256);           // 4200 blocks, zero dead threads
    yolov6_fused<<<grid, block, 0, stream>>>(gt, pred, anc,
                                             out_dist, out_ovl, out_giou,
                                             N, M, qcols, total);
}